// Round 1
// baseline (252.736 us; speedup 1.0000x reference)
//
#include <hip/hip_runtime.h>

#define BATCH 32
#define NAG   4096
#define FDIM  128
#define LREC  200      // L*DH floats per (b,n) record in hist_feat
#define KSEL  8

// ---------------------------------------------------------------------------
// Kernel 1: one wave (64 lanes) per agent. Computes the full score for
// agent (b, n), n in [1, 4095]. scores[b*4096 + n]; slot n==0 set to +inf.
// ---------------------------------------------------------------------------
__global__ __launch_bounds__(256) void score_kernel(
    const float* __restrict__ x,     // (B, N, FDIM)
    const float* __restrict__ hf,    // (B, N, L, DH)
    const float* __restrict__ he,    // (B, N, FDIM)
    float* __restrict__ scores)      // (B, N)
{
    const int gtid = blockIdx.x * 256 + threadIdx.x;
    const int wave = gtid >> 6;          // global wave id = b*4096 + n
    const int lane = threadIdx.x & 63;
    const int b = wave >> 12;            // / 4096
    const int n = wave & (NAG - 1);
    if (b >= BATCH) return;

    if (n == 0) {
        if (lane == 0) scores[(size_t)b * NAG] = 1e30f;
        return;
    }

    const size_t rown = (size_t)(b * NAG + n) * FDIM;
    const size_t rowc = (size_t)(b * NAG) * FDIM;

    const float2 a = ((const float2*)(x  + rown))[lane];
    const float2 c = ((const float2*)(x  + rowc))[lane];
    const float2 e = ((const float2*)(he + rown))[lane];
    const float2 f = ((const float2*)(he + rowc))[lane];

    const float dx = a.x - c.x, dy = a.y - c.y;
    float dist2 = dx * dx + dy * dy;
    float dotv  = e.x * f.x + e.y * f.y;
    float nn    = e.x * e.x + e.y * e.y;
    float cc    = f.x * f.x + f.y * f.y;

    #pragma unroll
    for (int m = 32; m; m >>= 1) {
        dist2 += __shfl_xor(dist2, m, 64);
        dotv  += __shfl_xor(dotv,  m, 64);
        nn    += __shfl_xor(nn,    m, 64);
        cc    += __shfl_xor(cc,    m, 64);
    }

    if (lane == 0) {
        const float dist = sqrtf(dist2);
        const float traj = dotv / (fmaxf(sqrtf(nn), 1e-8f) * fmaxf(sqrtf(cc), 1e-8f));

        // velocity cosine from hist_feat[..., 48:50, 0:2]
        const float* hn = hf + (size_t)(b * NAG + n) * LREC + 192;
        const float* h0 = hf + (size_t)(b * NAG)     * LREC + 192;
        const float dnx = hn[4] - hn[0], dny = hn[5] - hn[1];
        const float d0x = h0[4] - h0[0], d0y = h0[5] - h0[1];

        const float n0  = fmaxf(sqrtf(d0x * d0x + d0y * d0y), 1e-12f);
        const float cdx = d0x / n0 + 1e-8f, cdy = d0y / n0 + 1e-8f;
        const float nn2 = fmaxf(sqrtf(dnx * dnx + dny * dny), 1e-12f);
        const float odx = dnx / nn2 + 1e-8f, ody = dny / nn2 + 1e-8f;

        const float num = odx * cdx + ody * cdy;
        const float den = fmaxf(sqrtf(odx * odx + ody * ody), 1e-8f) *
                          fmaxf(sqrtf(cdx * cdx + cdy * cdy), 1e-8f);
        const float vel = num / den;

        const float score = 0.3f * dist
                          + 0.5f * (1.0f - fmaxf(vel,  0.0f))
                          + 0.4f * (1.0f - fmaxf(traj, 0.0f));
        scores[(size_t)b * NAG + n] = score;
    }
}

// ---------------------------------------------------------------------------
// Kernel 2: one block per batch. 8-round iterative arg-min over the 4096
// score slots (tie-break: lower index, matching jax.lax.top_k), then gather
// the selected agent rows and write indices (as float) after the rows.
// Output layout: d_out[0 .. B*8*128) = closest_agents, then B*8 indices.
// ---------------------------------------------------------------------------
__global__ __launch_bounds__(256) void topk_gather_kernel(
    const float* __restrict__ scores,
    const float* __restrict__ x,
    float* __restrict__ out)
{
    const int b   = blockIdx.x;
    const int tid = threadIdx.x;

    __shared__ float s[NAG];
    __shared__ int   sel[KSEL];
    __shared__ float red_s[4];
    __shared__ int   red_i[4];

    for (int i = tid; i < NAG; i += 256)
        s[i] = scores[(size_t)b * NAG + i];
    __syncthreads();

    for (int r = 0; r < KSEL; ++r) {
        float best = 1e30f;
        int   bi   = 0x7fffffff;
        for (int i = tid; i < NAG; i += 256) {
            const float v = s[i];
            if (v < best || (v == best && i < bi)) { best = v; bi = i; }
        }
        #pragma unroll
        for (int m = 32; m; m >>= 1) {
            const float ov = __shfl_xor(best, m, 64);
            const int   oi = __shfl_xor(bi,   m, 64);
            if (ov < best || (ov == best && oi < bi)) { best = ov; bi = oi; }
        }
        if ((tid & 63) == 0) { red_s[tid >> 6] = best; red_i[tid >> 6] = bi; }
        __syncthreads();
        if (tid == 0) {
            float bb = red_s[0]; int ii = red_i[0];
            #pragma unroll
            for (int w = 1; w < 4; ++w)
                if (red_s[w] < bb || (red_s[w] == bb && red_i[w] < ii)) {
                    bb = red_s[w]; ii = red_i[w];
                }
            sel[r] = ii;
            s[ii] = 1e30f;   // exclude from later rounds
        }
        __syncthreads();
    }

    // gather 8 rows x 128 floats
    for (int e2 = tid; e2 < KSEL * FDIM; e2 += 256) {
        const int j = e2 >> 7;     // which of the 8
        const int d = e2 & 127;
        const int n = sel[j];
        out[((size_t)b * KSEL + j) * FDIM + d] = x[(size_t)(b * NAG + n) * FDIM + d];
    }
    if (tid < KSEL)
        out[(size_t)BATCH * KSEL * FDIM + b * KSEL + tid] = (float)(sel[tid] - 1);
}

extern "C" void kernel_launch(void* const* d_in, const int* in_sizes, int n_in,
                              void* d_out, int out_size, void* d_ws, size_t ws_size,
                              hipStream_t stream) {
    const float* x  = (const float*)d_in[0];   // (B, N, FDIM)
    const float* hf = (const float*)d_in[1];   // (B, N, L, DH)
    const float* he = (const float*)d_in[2];   // (B, N, FDIM)
    float* out = (float*)d_out;
    float* scores = (float*)d_ws;              // B*N floats = 512 KB

    // Phase 1: B*N waves, 4 waves per 256-thread block
    const int total_waves  = BATCH * NAG;
    const int blocks1      = total_waves / 4;  // 32768
    score_kernel<<<blocks1, 256, 0, stream>>>(x, hf, he, scores);

    // Phase 2: one block per batch
    topk_gather_kernel<<<BATCH, 256, 0, stream>>>(scores, x, out);
}

// Round 2
// 234.585 us; speedup vs baseline: 1.0774x; 1.0774x over previous
//
#include <hip/hip_runtime.h>

#define BATCH 32
#define NAG   4096
#define FDIM  128
#define LREC  200      // L*DH floats per (b,n) record in hist_feat
#define KSEL  8

// ---------------------------------------------------------------------------
// Kernel 1: one wave handles TWO agents (32 lanes each, float4/lane = 128
// dims). Butterfly reduction stays within each 32-lane half (masks 16..1).
// Epilogue (sqrt/div-heavy) runs once per wave with 2 active lanes.
// scores[b*4096 + n]; slot n==0 set to +inf.
// ---------------------------------------------------------------------------
__global__ __launch_bounds__(256) void score_kernel(
    const float* __restrict__ x,     // (B, N, FDIM)
    const float* __restrict__ hf,    // (B, N, L, DH)
    const float* __restrict__ he,    // (B, N, FDIM)
    float* __restrict__ scores)      // (B, N)
{
    const int gtid = blockIdx.x * 256 + threadIdx.x;
    const int wave = gtid >> 6;          // 32*2048 waves total
    const int lane = threadIdx.x & 63;
    const int half = lane >> 5;          // which agent of the pair
    const int sub  = lane & 31;          // lane within the half

    const int b = wave >> 11;            // / 2048 pairs per batch
    const int p = wave & 2047;
    const int n = 2 * p + half;          // agent id in [0, 4096)

    const size_t rown = ((size_t)(b << 12) + n) * FDIM;
    const size_t rowc = ((size_t)(b << 12)) * FDIM;

    const float4 a = *(const float4*)(x  + rown + sub * 4);
    const float4 c = *(const float4*)(x  + rowc + sub * 4);
    const float4 e = *(const float4*)(he + rown + sub * 4);
    const float4 f = *(const float4*)(he + rowc + sub * 4);

    const float dx0 = a.x - c.x, dx1 = a.y - c.y, dx2 = a.z - c.z, dx3 = a.w - c.w;
    float dist2 = dx0 * dx0 + dx1 * dx1 + dx2 * dx2 + dx3 * dx3;
    float dotv  = e.x * f.x + e.y * f.y + e.z * f.z + e.w * f.w;
    float nn    = e.x * e.x + e.y * e.y + e.z * e.z + e.w * e.w;
    float cc    = f.x * f.x + f.y * f.y + f.z * f.z + f.w * f.w;

    #pragma unroll
    for (int m = 16; m; m >>= 1) {       // stays within each 32-lane half
        dist2 += __shfl_xor(dist2, m, 64);
        dotv  += __shfl_xor(dotv,  m, 64);
        nn    += __shfl_xor(nn,    m, 64);
        cc    += __shfl_xor(cc,    m, 64);
    }

    if (sub == 0) {
        const float dist = sqrtf(dist2);
        const float traj = dotv / (fmaxf(sqrtf(nn), 1e-8f) * fmaxf(sqrtf(cc), 1e-8f));

        // velocity cosine from hist_feat[..., 48:50, 0:2]
        const float* hn = hf + ((size_t)(b << 12) + n) * LREC + 192;
        const float* h0 = hf + ((size_t)(b << 12)) * LREC + 192;
        const float2 hn0 = *(const float2*)(hn);
        const float2 hn1 = *(const float2*)(hn + 4);
        const float2 h00 = *(const float2*)(h0);
        const float2 h01 = *(const float2*)(h0 + 4);
        const float dnx = hn1.x - hn0.x, dny = hn1.y - hn0.y;
        const float d0x = h01.x - h00.x, d0y = h01.y - h00.y;

        const float n0  = fmaxf(sqrtf(d0x * d0x + d0y * d0y), 1e-12f);
        const float cdx = d0x / n0 + 1e-8f, cdy = d0y / n0 + 1e-8f;
        const float nn2 = fmaxf(sqrtf(dnx * dnx + dny * dny), 1e-12f);
        const float odx = dnx / nn2 + 1e-8f, ody = dny / nn2 + 1e-8f;

        const float num = odx * cdx + ody * cdy;
        const float den = fmaxf(sqrtf(odx * odx + ody * ody), 1e-8f) *
                          fmaxf(sqrtf(cdx * cdx + cdy * cdy), 1e-8f);
        const float vel = num / den;

        const float score = 0.3f * dist
                          + 0.5f * (1.0f - fmaxf(vel,  0.0f))
                          + 0.4f * (1.0f - fmaxf(traj, 0.0f));
        scores[(size_t)(b << 12) + n] = (n == 0) ? 1e30f : score;
    }
}

// ---------------------------------------------------------------------------
// Kernel 2: one block per batch. Scores cached in 16 registers/thread;
// 8 rounds of iterative arg-min (tie-break lower index = jax.lax.top_k),
// then gather rows + write indices (as float).
// ---------------------------------------------------------------------------
__global__ __launch_bounds__(256) void topk_gather_kernel(
    const float* __restrict__ scores,
    const float* __restrict__ x,
    float* __restrict__ out)
{
    const int b   = blockIdx.x;
    const int tid = threadIdx.x;

    float v[16];
    #pragma unroll
    for (int j = 0; j < 16; ++j)
        v[j] = scores[(size_t)(b << 12) + (j << 8) + tid];  // i = j*256 + tid

    __shared__ float red_s[4];
    __shared__ int   red_i[4];
    __shared__ int   sel[KSEL];

    for (int r = 0; r < KSEL; ++r) {
        float best = 1e30f;
        int   bi   = 0x7fffffff;
        #pragma unroll
        for (int j = 0; j < 16; ++j) {
            const int   i  = (j << 8) + tid;
            const float vv = v[j];
            if (vv < best || (vv == best && i < bi)) { best = vv; bi = i; }
        }
        #pragma unroll
        for (int m = 32; m; m >>= 1) {
            const float ov = __shfl_xor(best, m, 64);
            const int   oi = __shfl_xor(bi,   m, 64);
            if (ov < best || (ov == best && oi < bi)) { best = ov; bi = oi; }
        }
        if ((tid & 63) == 0) { red_s[tid >> 6] = best; red_i[tid >> 6] = bi; }
        __syncthreads();
        if (tid == 0) {
            float bb = red_s[0]; int ii = red_i[0];
            #pragma unroll
            for (int w = 1; w < 4; ++w)
                if (red_s[w] < bb || (red_s[w] == bb && red_i[w] < ii)) {
                    bb = red_s[w]; ii = red_i[w];
                }
            sel[r] = ii;
        }
        __syncthreads();
        const int w = sel[r];
        if ((w & 255) == tid) v[w >> 8] = 1e30f;   // exclude winner locally
    }

    // gather 8 rows x 128 floats
    for (int e2 = tid; e2 < KSEL * FDIM; e2 += 256) {
        const int j = e2 >> 7;
        const int d = e2 & 127;
        const int n = sel[j];
        out[((size_t)b * KSEL + j) * FDIM + d] = x[((size_t)(b << 12) + n) * FDIM + d];
    }
    if (tid < KSEL)
        out[(size_t)BATCH * KSEL * FDIM + b * KSEL + tid] = (float)(sel[tid] - 1);
}

extern "C" void kernel_launch(void* const* d_in, const int* in_sizes, int n_in,
                              void* d_out, int out_size, void* d_ws, size_t ws_size,
                              hipStream_t stream) {
    const float* x  = (const float*)d_in[0];   // (B, N, FDIM)
    const float* hf = (const float*)d_in[1];   // (B, N, L, DH)
    const float* he = (const float*)d_in[2];   // (B, N, FDIM)
    float* out = (float*)d_out;
    float* scores = (float*)d_ws;              // B*N floats = 512 KB

    // Phase 1: 32 batches x 2048 agent-pairs = 65536 waves, 4 waves/block
    const int blocks1 = (BATCH * (NAG / 2) * 64) / 256;   // 16384
    score_kernel<<<blocks1, 256, 0, stream>>>(x, hf, he, scores);

    // Phase 2: one block per batch
    topk_gather_kernel<<<BATCH, 256, 0, stream>>>(scores, x, out);
}